// Round 18
// baseline (1035.272 us; speedup 1.0000x reference)
//
#include <hip/hip_runtime.h>

#define T_LEN 2048
#define HID 64
#define EMB 128
#define WD 8
#define NWIN (T_LEN / WD)    // 256
#define NPH (NWIN + 4)

typedef _Float16 half2_t __attribute__((ext_vector_type(2)));
typedef _Float16 f16x8  __attribute__((ext_vector_type(8)));
typedef float    f32x4  __attribute__((ext_vector_type(4)));
typedef unsigned uint4v __attribute__((ext_vector_type(4)));

#if __has_builtin(__builtin_amdgcn_exp2f)
#define EXP2F(x) __builtin_amdgcn_exp2f(x)
#else
#define EXP2F(x) exp2f(x)
#endif
#if __has_builtin(__builtin_amdgcn_rcpf)
#define RCPF(x) __builtin_amdgcn_rcpf(x)
#else
#define RCPF(x) (1.0f / (x))
#endif

#define LOG2E 1.4426950408889634f

__device__ __forceinline__ float fdot2(unsigned a, unsigned b, float c) {
    return __builtin_amdgcn_fdot2(__builtin_bit_cast(half2_t, a),
                                  __builtin_bit_cast(half2_t, b), c, false);
}

// Full-row 64-MAC dot: 8 weight quads vs 8 gathered-h quads, 4 chains.
__device__ __forceinline__ float dotrow(const uint4v* w, const uint4v* g, float init) {
    float a0 = init, a1 = 0.f, a2 = 0.f, a3 = 0.f;
    #pragma unroll
    for (int q = 0; q < 8; ++q) {
        a0 = fdot2(w[q][0], g[q][0], a0);
        a1 = fdot2(w[q][1], g[q][1], a1);
        a2 = fdot2(w[q][2], g[q][2], a2);
        a3 = fdot2(w[q][3], g[q][3], a3);
    }
    return (a0 + a1) + (a2 + a3);
}

__device__ __forceinline__ uint4v pack8(float4 a, float4 b, float s) {
    half2_t h0{(_Float16)(a.x * s), (_Float16)(a.y * s)};
    half2_t h1{(_Float16)(a.z * s), (_Float16)(a.w * s)};
    half2_t h2{(_Float16)(b.x * s), (_Float16)(b.y * s)};
    half2_t h3{(_Float16)(b.z * s), (_Float16)(b.w * s)};
    uint4v q;
    q[0] = __builtin_bit_cast(unsigned, h0);
    q[1] = __builtin_bit_cast(unsigned, h1);
    q[2] = __builtin_bit_cast(unsigned, h2);
    q[3] = __builtin_bit_cast(unsigned, h3);
    return q;
}
__device__ __forceinline__ f16x8 pack8f(float4 a, float4 b, float s) {
    f16x8 r;
    r[0] = (_Float16)(a.x * s); r[1] = (_Float16)(a.y * s);
    r[2] = (_Float16)(a.z * s); r[3] = (_Float16)(a.w * s);
    r[4] = (_Float16)(b.x * s); r[5] = (_Float16)(b.y * s);
    r[6] = (_Float16)(b.z * s); r[7] = (_Float16)(b.w * s);
    return r;
}

// One 64-float weight row -> 8 packed quads, exp2-space prescaled.
__device__ __forceinline__ void cvt8(const float* __restrict__ Wp, float s, uint4v* dst) {
    const float4* p = reinterpret_cast<const float4*>(Wp);
    #pragma unroll
    for (int k = 0; k < 8; ++k) dst[k] = pack8(p[2 * k], p[2 * k + 1], s);
}

// ROUND 18 = R15 (977us best: WD=8, barrier/phase, balanced) with the ih
// GEMMs moved to the MFMA pipe (MfmaUtil was 0.0 all session; MFMA+VALU
// co-schedule per-SIMD). Per phase each ih product is [256x64]x[64x8]:
// 16 N-tiles x 2 K-chunks of mfma_f32_16x16x32_f16, split across 2 waves.
//   A (h-window): A[m=step][k=hid]; lane reads 8 contiguous f16 at
//     (lane&15)*HID + kc*32 + (lane>>4)*8 — one ds_read_b128 per kc.
//     Ring rows 8..15 are permanent zeros (M=16 pad).
//   B (weights): B[k][n=row]; lane holds row t*16+(lane&15), k-chunk
//     (lane>>4)*8 — 16 f16x8 fragments in registers from init.
//   D: col=lane&15 = row-in-tile, row=(lane>>4)*4+r = step; lanes kq<2
//     scatter steps 0..7 into pbuf[j][cls][L] (layout C-waves already read).
// Roles: wv0/1/2 = C0/C1/C2 (R15 verbatim: 4 whh rows fdot2, in-lane gates,
// scalar cell). wv4/wv5 = p1 rows 0..127/128..255; wv6/wv3 = p2 halves;
// wv7 spare. C-waves become near-sole VALU issuers on S0-2 -> fdot2
// contention drops ~4->~2 cyc. One barrier/phase (R16/R17 showed WD=16 and
// flag-sync both regress).
__global__ __launch_bounds__(512)
__attribute__((amdgpu_waves_per_eu(2, 2)))
void lstm3_fused(
    const float* __restrict__ x,
    const float* __restrict__ Wih0, const float* __restrict__ Whh0,
    const float* __restrict__ bih0, const float* __restrict__ bhh0,
    const float* __restrict__ Wih1, const float* __restrict__ Whh1,
    const float* __restrict__ bih1, const float* __restrict__ bhh1,
    const float* __restrict__ Wih2, const float* __restrict__ Whh2,
    const float* __restrict__ bih2, const float* __restrict__ bhh2,
    const float* __restrict__ fcW,  const float* __restrict__ fcb,
    float* __restrict__ out)
{
    const int b   = blockIdx.x;
    const int tid = threadIdx.x;
    const int wv  = tid >> 6;          // 0..7 (wave-uniform role)
    const int L   = tid & 63;
    const int nl  = L & 15;            // MFMA n / m low index
    const int kq  = L >> 4;            // MFMA k-quad 0..3

    // h rings: [parity][16 steps][HID]; steps 8..15 stay zero (MFMA M-pad).
    __shared__ __align__(16) _Float16 h0ring[2][16][HID];
    __shared__ __align__(16) _Float16 h1ring[2][16][HID];
    __shared__ __align__(16) _Float16 h2ring[2][HID];
    __shared__ float p1buf[2][WD][4][HID];
    __shared__ float p2buf[2][WD][4][HID];
    __shared__ __align__(16) float xs[T_LEN];

    {
        const float4* xg4 = reinterpret_cast<const float4*>(x + b * T_LEN);
        reinterpret_cast<float4*>(xs)[tid] = xg4[tid];
        unsigned* z0 = reinterpret_cast<unsigned*>(h0ring);
        unsigned* z1 = reinterpret_cast<unsigned*>(h1ring);
        z0[tid] = 0u; z0[tid + 512] = 0u;     // 2*16*64 f16 = 1024 dwords
        z1[tid] = 0u; z1[tid + 512] = 0u;
        if (tid < 64) reinterpret_cast<unsigned*>(h2ring)[tid] = 0u;
    }

    const float sI = -LOG2E, sF = -LOG2E, sG = -2.f * LOG2E, sO = -LOG2E;
    const float scl[4] = {sI, sF, sG, sO};

    uint4v w[4][8];                    // C-waves: 4 whh rows
    f16x8 Bf[8][2];                    // M-waves: 8 N-tiles x 2 K-chunks
    float bias4[4] = {0.f, 0.f, 0.f, 0.f};
    float wx4[4]   = {0.f, 0.f, 0.f, 0.f};

    if (wv < 3) {                      // C_l: whh_l all 4 gate rows
        const float* Wh = (wv == 0) ? Whh0 : (wv == 1) ? Whh1 : Whh2;
        const float* bi = (wv == 0) ? bih0 : (wv == 1) ? bih1 : bih2;
        const float* bh = (wv == 0) ? bhh0 : (wv == 1) ? bhh1 : bhh2;
        #pragma unroll
        for (int c = 0; c < 4; ++c) {
            cvt8(Wh + (c * 64 + L) * 64, scl[c], w[c]);
            bias4[c] = (bi[c * 64 + L] + bh[c * 64 + L]) * scl[c];
        }
        if (wv == 0) {
            #pragma unroll
            for (int c = 0; c < 4; ++c) wx4[c] = Wih0[c * 64 + L] * scl[c];
        }
    } else if (wv != 7) {
        // MFMA producer waves: wv4 = p1 half0, wv5 = p1 half1,
        //                      wv6 = p2 half0, wv3 = p2 half1.
        const bool isP1 = (wv == 4 || wv == 5);
        const int  half = (wv == 5 || wv == 3) ? 1 : 0;
        const float* W  = isP1 ? Wih1 : Wih2;
        #pragma unroll
        for (int t = 0; t < 8; ++t) {
            const int row = half * 128 + t * 16 + nl;
            const float sc = scl[row >> 6];
            #pragma unroll
            for (int kc = 0; kc < 2; ++kc) {
                const float4* p = reinterpret_cast<const float4*>(
                    W + row * 64 + kc * 32 + kq * 8);
                Bf[t][kc] = pack8f(p[0], p[1], sc);
            }
        }
    }

    float cst = 0.f;
    __syncthreads();

    for (int ph = 0; ph < NPH; ++ph) {
        const int par = ph & 1;

        if (wv == 0) {
            if (ph < NWIN) {           // h0 window ph
                _Float16* cur = &h0ring[par][0][0];
                const _Float16* prv = &h0ring[par ^ 1][0][0];
                const int tb = ph * WD;
                #pragma unroll
                for (int j = 0; j < WD; ++j) {
                    const uint4v* hp = reinterpret_cast<const uint4v*>(
                        (j == 0) ? (prv + (WD - 1) * HID) : (cur + (j - 1) * HID));
                    uint4v g[8];
                    #pragma unroll
                    for (int k = 0; k < 8; ++k) g[k] = hp[k];
                    float xv = xs[tb + j];
                    float d0 = dotrow(w[0], g, fmaf(wx4[0], xv, bias4[0]));
                    float d1 = dotrow(w[1], g, fmaf(wx4[1], xv, bias4[1]));
                    float d2 = dotrow(w[2], g, fmaf(wx4[2], xv, bias4[2]));
                    float d3 = dotrow(w[3], g, fmaf(wx4[3], xv, bias4[3]));
                    float ai = RCPF(1.f + EXP2F(d0));
                    float af = RCPF(1.f + EXP2F(d1));
                    float ag = fmaf(2.f, RCPF(1.f + EXP2F(d2)), -1.f);
                    float ao = RCPF(1.f + EXP2F(d3));
                    cst = fmaf(af, cst, ai * ag);
                    float tc = fmaf(2.f, RCPF(1.f + EXP2F(-2.f * LOG2E * cst)), -1.f);
                    cur[j * HID + L] = (_Float16)(ao * tc);
                }
            }
        } else if (wv == 1) {
            if (ph >= 2 && ph < NWIN + 2) {    // h1 window ph-2
                _Float16* cur = &h1ring[par][0][0];
                const _Float16* prv = &h1ring[par ^ 1][0][0];
                const float (*pb)[4][HID] = p1buf[par];
                #pragma unroll
                for (int j = 0; j < WD; ++j) {
                    const uint4v* hp = reinterpret_cast<const uint4v*>(
                        (j == 0) ? (prv + (WD - 1) * HID) : (cur + (j - 1) * HID));
                    uint4v g[8];
                    #pragma unroll
                    for (int k = 0; k < 8; ++k) g[k] = hp[k];
                    float d0 = dotrow(w[0], g, bias4[0] + pb[j][0][L]);
                    float d1 = dotrow(w[1], g, bias4[1] + pb[j][1][L]);
                    float d2 = dotrow(w[2], g, bias4[2] + pb[j][2][L]);
                    float d3 = dotrow(w[3], g, bias4[3] + pb[j][3][L]);
                    float ai = RCPF(1.f + EXP2F(d0));
                    float af = RCPF(1.f + EXP2F(d1));
                    float ag = fmaf(2.f, RCPF(1.f + EXP2F(d2)), -1.f);
                    float ao = RCPF(1.f + EXP2F(d3));
                    cst = fmaf(af, cst, ai * ag);
                    float tc = fmaf(2.f, RCPF(1.f + EXP2F(-2.f * LOG2E * cst)), -1.f);
                    cur[j * HID + L] = (_Float16)(ao * tc);
                }
            }
        } else if (wv == 2) {
            if (ph >= 4) {                     // h2 window ph-4
                const float (*pb)[4][HID] = p2buf[par];
                #pragma unroll
                for (int j = 0; j < WD; ++j) {
                    const uint4v* hp = reinterpret_cast<const uint4v*>(
                        &h2ring[(j & 1) ^ 1][0]);
                    uint4v g[8];
                    #pragma unroll
                    for (int k = 0; k < 8; ++k) g[k] = hp[k];
                    float d0 = dotrow(w[0], g, bias4[0] + pb[j][0][L]);
                    float d1 = dotrow(w[1], g, bias4[1] + pb[j][1][L]);
                    float d2 = dotrow(w[2], g, bias4[2] + pb[j][2][L]);
                    float d3 = dotrow(w[3], g, bias4[3] + pb[j][3][L]);
                    float ai = RCPF(1.f + EXP2F(d0));
                    float af = RCPF(1.f + EXP2F(d1));
                    float ag = fmaf(2.f, RCPF(1.f + EXP2F(d2)), -1.f);
                    float ao = RCPF(1.f + EXP2F(d3));
                    cst = fmaf(af, cst, ai * ag);
                    float tc = fmaf(2.f, RCPF(1.f + EXP2F(-2.f * LOG2E * cst)), -1.f);
                    h2ring[j & 1][L] = (_Float16)(ao * tc);
                }
            }
        } else if (wv != 7) {
            // MFMA producers: D[step][row] = sum_k h[step][k] * W[row][k].
            const bool isP1 = (wv == 4 || wv == 5);
            const int  half = (wv == 5 || wv == 3) ? 1 : 0;
            const bool act  = isP1 ? (ph >= 1 && ph < NWIN + 1)
                                   : (ph >= 3 && ph < NWIN + 3);
            if (act) {
                const _Float16* hb = isP1 ? &h0ring[par ^ 1][0][0]
                                          : &h1ring[par ^ 1][0][0];
                // A fragments: one per K-chunk (shared across all N-tiles).
                f16x8 a0 = *reinterpret_cast<const f16x8*>(hb + nl * HID + kq * 8);
                f16x8 a1 = *reinterpret_cast<const f16x8*>(hb + nl * HID + 32 + kq * 8);
                float (*po)[4][HID] = isP1 ? p1buf[par ^ 1] : p2buf[par ^ 1];
                #pragma unroll
                for (int t = 0; t < 8; ++t) {
                    f32x4 acc = {0.f, 0.f, 0.f, 0.f};
                    acc = __builtin_amdgcn_mfma_f32_16x16x32_f16(a0, Bf[t][0], acc, 0, 0, 0);
                    acc = __builtin_amdgcn_mfma_f32_16x16x32_f16(a1, Bf[t][1], acc, 0, 0, 0);
                    // D: step = kq*4 + r (valid < 8 -> kq < 2), col = row-in-tile.
                    if (kq < 2) {
                        const int cls = half * 2 + (t >> 2);
                        const int rl  = (t & 3) * 16 + nl;
                        #pragma unroll
                        for (int r = 0; r < 4; ++r)
                            po[kq * 4 + r][cls][rl] = acc[r];
                    }
                }
            }
        }

        __syncthreads();   // publish window: h rings + p-buffers
    }

    // Final FC (f32): h2[2047] -> slot 7&1 = 1.
    if (tid < EMB) {
        float acc = fcb[tid];
        const _Float16* hf = &h2ring[1][0];
        const float4* W4 = reinterpret_cast<const float4*>(fcW + tid * HID);
        #pragma unroll
        for (int k = 0; k < 16; ++k) {
            float4 wv4 = W4[k];
            acc = fmaf(wv4.x, (float)hf[4 * k + 0], acc);
            acc = fmaf(wv4.y, (float)hf[4 * k + 1], acc);
            acc = fmaf(wv4.z, (float)hf[4 * k + 2], acc);
            acc = fmaf(wv4.w, (float)hf[4 * k + 3], acc);
        }
        out[b * EMB + tid] = acc;
    }
}

extern "C" void kernel_launch(void* const* d_in, const int* in_sizes, int n_in,
                              void* d_out, int out_size, void* d_ws, size_t ws_size,
                              hipStream_t stream) {
    const float* x    = (const float*)d_in[0];
    const float* Wih0 = (const float*)d_in[1];
    const float* Whh0 = (const float*)d_in[2];
    const float* bih0 = (const float*)d_in[3];
    const float* bhh0 = (const float*)d_in[4];
    const float* Wih1 = (const float*)d_in[5];
    const float* Whh1 = (const float*)d_in[6];
    const float* bih1 = (const float*)d_in[7];
    const float* bhh1 = (const float*)d_in[8];
    const float* Wih2 = (const float*)d_in[9];
    const float* Whh2 = (const float*)d_in[10];
    const float* bih2 = (const float*)d_in[11];
    const float* bhh2 = (const float*)d_in[12];
    const float* fcW  = (const float*)d_in[13];
    const float* fcb  = (const float*)d_in[14];
    float* out = (float*)d_out;

    lstm3_fused<<<dim3(256), dim3(512), 0, stream>>>(
        x, Wih0, Whh0, bih0, bhh0,
        Wih1, Whh1, bih1, bhh1,
        Wih2, Whh2, bih2, bhh2,
        fcW, fcb, out);
}